// Round 1
// 165.338 us; speedup vs baseline: 1.0117x; 1.0117x over previous
//
#include <hip/hip_runtime.h>
#include <math.h>

#define BB 4
#define CC 256
#define NHEAD 4
#define DH 32
#define NN 4096
#define HID 128

typedef _Float16 f16;
typedef _Float16 f16x8 __attribute__((ext_vector_type(8)));
typedef _Float16 f16x4 __attribute__((ext_vector_type(4)));
typedef float f32x4 __attribute__((ext_vector_type(4)));

#define QPRESCALE 14.42695041f
#define NSHIFT 14.42695041f

#if __has_builtin(__builtin_amdgcn_exp2f)
#define EXP2F(x) __builtin_amdgcn_exp2f(x)
#else
#define EXP2F(x) __expf((x)*0.6931471805599453f)
#endif

__device__ __forceinline__ f16x8 cvt8(const float* p) {
    float4 a = *(const float4*)p;
    float4 b = *(const float4*)(p + 4);
    f16x8 r;
    r[0] = (f16)a.x; r[1] = (f16)a.y; r[2] = (f16)a.z; r[3] = (f16)a.w;
    r[4] = (f16)b.x; r[5] = (f16)b.y; r[6] = (f16)b.z; r[7] = (f16)b.w;
    return r;
}

// ---------------- kernel 1: fused qkv GEMM + l2norm + layout ----------------
__global__ __launch_bounds__(256) void qkv_fused(const float* __restrict__ x,
                                                 const float* __restrict__ wq,
                                                 f16* __restrict__ qh,
                                                 f16* __restrict__ kh,
                                                 f16* __restrict__ vh) {
    int wave = threadIdx.x >> 6, lane = threadIdx.x & 63;
    int quad = lane >> 4, col = lane & 15;
    int b = blockIdx.z;
    int o0 = blockIdx.y * 64;
    int i0 = blockIdx.x * 128 + wave * 32;
    const float* xb = x + (size_t)b * CC * NN;

    f32x4 c[4][2];
#pragma unroll
    for (int mt = 0; mt < 4; mt++)
#pragma unroll
        for (int nt = 0; nt < 2; nt++) c[mt][nt] = f32x4{0.f, 0.f, 0.f, 0.f};

#pragma unroll
    for (int k0 = 0; k0 < CC; k0 += 32) {
        f16x8 a[4];
#pragma unroll
        for (int mt = 0; mt < 4; mt++)
            a[mt] = cvt8(wq + (size_t)(o0 + mt * 16 + col) * CC + k0 + quad * 8);
#pragma unroll
        for (int nt = 0; nt < 2; nt++) {
            const float* xc = xb + (size_t)(k0 + quad * 8) * NN + i0 + nt * 16 + col;
            f16x8 bf;
#pragma unroll
            for (int j = 0; j < 8; j++) bf[j] = (f16)xc[(size_t)j * NN];
#pragma unroll
            for (int mt = 0; mt < 4; mt++)
                c[mt][nt] = __builtin_amdgcn_mfma_f32_16x16x32_f16(a[mt], bf, c[mt][nt], 0, 0, 0);
        }
    }

    if (o0 < 256) {
        int isQ = (o0 < 128);
        int obase = isQ ? o0 : (o0 - 128);
        f16* dst = isQ ? qh : kh;
        float pre = isQ ? QPRESCALE : 1.0f;
#pragma unroll
        for (int nt = 0; nt < 2; nt++) {
#pragma unroll
            for (int hh = 0; hh < 2; hh++) {
                float ss = 0.f;
#pragma unroll
                for (int m2 = 0; m2 < 2; m2++)
#pragma unroll
                    for (int r = 0; r < 4; r++) {
                        float v = c[hh * 2 + m2][nt][r];
                        ss = fmaf(v, v, ss);
                    }
                ss += __shfl_xor(ss, 16);
                ss += __shfl_xor(ss, 32);
                float inv = pre / fmaxf(sqrtf(ss), 1e-12f);
                int h = (obase + hh * 32) >> 5;
                size_t row = ((size_t)(b * 4 + h) * NN + i0 + nt * 16 + col) * 32;
#pragma unroll
                for (int m2 = 0; m2 < 2; m2++) {
                    f16x4 st;
#pragma unroll
                    for (int r = 0; r < 4; r++) st[r] = (f16)(c[hh * 2 + m2][nt][r] * inv);
                    *(f16x4*)(dst + row + m2 * 16 + quad * 4) = st;
                }
            }
        }
    } else {
        int o2 = o0 - 256;
#pragma unroll
        for (int nt = 0; nt < 2; nt++) {
            int i = i0 + nt * 16 + col;
#pragma unroll
            for (int mt = 0; mt < 4; mt++) {
                int h = (o2 + mt * 16) >> 5;
                int d = (mt & 1) * 16 + quad * 4;
#pragma unroll
                for (int r = 0; r < 4; r++)
                    vh[((size_t)(b * 4 + h) * 32 + d + r) * NN + i] = (f16)c[mt][nt][r];
            }
        }
    }
}

// ---------------- kernel 2: LDS-staged MFMA flash attention, key-split ------
// Latency-bound at 2 blocks/CU (R0 counters: Mfma 31%, VALU 44%, Occ 17.8%).
// Key-split: SPLIT x blocks, each handles NN/SPLIT keys. Per-CU LDS traffic is
// unchanged (frag reads are per-wave-per-tile; SPLITx waves x 1/SPLIT tiles),
// unlike a q-split which would double it. Fixed-shift softmax (scores bounded
// by SCALE since q,k are l2-normalized) -> partials combine as sum(o)/sum(l).
#define KROW 40
#define VROW 72

struct KV32 {
    f16x8 k0, k1;
    f16x4 v0n0, v0n1, v1n0, v1n1;
};

__device__ __forceinline__ KV32 lds_frags(const f16* kl, const f16* vl,
                                          int jb, int col, int quad) {
    KV32 f;
    f.k0 = *(const f16x8*)(kl + (jb + col) * KROW + quad * 8);
    f.k1 = *(const f16x8*)(kl + (jb + 16 + col) * KROW + quad * 8);
    f.v0n0 = *(const f16x4*)(vl + col * VROW + jb + quad * 4);
    f.v0n1 = *(const f16x4*)(vl + (16 + col) * VROW + jb + quad * 4);
    f.v1n0 = *(const f16x4*)(vl + col * VROW + jb + 16 + quad * 4);
    f.v1n1 = *(const f16x4*)(vl + (16 + col) * VROW + jb + 16 + quad * 4);
    return f;
}

__device__ __forceinline__ f16x4 expblk(f32x4 s, float& lacc) {
    float p0 = EXP2F(s[0]), p1 = EXP2F(s[1]);
    float p2 = EXP2F(s[2]), p3 = EXP2F(s[3]);
    lacc += (p0 + p1) + (p2 + p3);
    f16x4 r;
    r[0] = (f16)p0; r[1] = (f16)p1; r[2] = (f16)p2; r[3] = (f16)p3;
    return r;
}

__device__ __forceinline__ void compute32(const KV32& f, f16x8 qB0, f16x8 qB1,
                                          f32x4& o00, f32x4& o01,
                                          f32x4& o10, f32x4& o11,
                                          float& l0, float& l1) {
    const f32x4 zs = {-NSHIFT, -NSHIFT, -NSHIFT, -NSHIFT};
    f32x4 s00 = __builtin_amdgcn_mfma_f32_16x16x32_f16(f.k0, qB0, zs, 0, 0, 0);
    f32x4 s10 = __builtin_amdgcn_mfma_f32_16x16x32_f16(f.k0, qB1, zs, 0, 0, 0);
    f32x4 s01 = __builtin_amdgcn_mfma_f32_16x16x32_f16(f.k1, qB0, zs, 0, 0, 0);
    f32x4 s11 = __builtin_amdgcn_mfma_f32_16x16x32_f16(f.k1, qB1, zs, 0, 0, 0);
    f16x4 p00 = expblk(s00, l0);
    f16x4 p10 = expblk(s10, l1);
    f16x4 p01 = expblk(s01, l0);
    f16x4 p11 = expblk(s11, l1);
    o00 = __builtin_amdgcn_mfma_f32_16x16x16f16(p00, f.v0n0, o00, 0, 0, 0);
    o01 = __builtin_amdgcn_mfma_f32_16x16x16f16(p00, f.v0n1, o01, 0, 0, 0);
    o10 = __builtin_amdgcn_mfma_f32_16x16x16f16(p10, f.v0n0, o10, 0, 0, 0);
    o11 = __builtin_amdgcn_mfma_f32_16x16x16f16(p10, f.v0n1, o11, 0, 0, 0);
    o00 = __builtin_amdgcn_mfma_f32_16x16x16f16(p01, f.v1n0, o00, 0, 0, 0);
    o01 = __builtin_amdgcn_mfma_f32_16x16x16f16(p01, f.v1n1, o01, 0, 0, 0);
    o10 = __builtin_amdgcn_mfma_f32_16x16x16f16(p11, f.v1n0, o10, 0, 0, 0);
    o11 = __builtin_amdgcn_mfma_f32_16x16x16f16(p11, f.v1n1, o11, 0, 0, 0);
}

template <int SPLIT>
__global__ __launch_bounds__(256, 4) void attn_mfma(const f16* __restrict__ qh,
                                                    const f16* __restrict__ kh,
                                                    const f16* __restrict__ vh,
                                                    float* __restrict__ op,
                                                    float* __restrict__ lp,
                                                    f16* __restrict__ att16) {
    __shared__ __align__(16) f16 klds[2][64 * KROW];
    __shared__ __align__(16) f16 vlds[2][32 * VROW];
    int t = threadIdx.x;
    int wave = t >> 6, lane = t & 63;
    int quad = lane >> 4, col = lane & 15;

    // 512*SPLIT blocks; xcd grouping keeps K/V L2-resident (2 bh per XCD).
    int bid = blockIdx.x;
    int xcd = bid & 7;
    int slot = bid >> 3;                      // 0 .. 64*SPLIT-1
    int bh = xcd * 2 + slot / (32 * SPLIT);   // 0..15
    int rem = slot % (32 * SPLIT);
    int s = rem >> 5;                         // 0..SPLIT-1
    int i0 = (rem & 31) * 128;
    int iw = i0 + wave * 32;

    const int NT = 64 / SPLIT;                // 64-key tiles per block
    int kbase = s * (NN / SPLIT);

    const f16* qb = qh + (size_t)bh * NN * 32;
    const f16* kb = kh + (size_t)bh * NN * 32 + (size_t)kbase * 32;
    const f16* vb = vh + (size_t)bh * 32 * NN + kbase;

    f16x8 qB0 = *(const f16x8*)(qb + (size_t)(iw + col) * 32 + quad * 8);
    f16x8 qB1 = *(const f16x8*)(qb + (size_t)(iw + 16 + col) * 32 + quad * 8);

    f32x4 o00 = {0.f, 0.f, 0.f, 0.f}, o01 = o00, o10 = o00, o11 = o00;
    float l0 = 0.f, l1 = 0.f;

    int ktr = t >> 2, kts = t & 3;
    int vtr = t >> 3, vts = t & 7;

    f16x8 kr, vr;
    kr = *(const f16x8*)(kb + (size_t)(0 + ktr) * 32 + kts * 8);
    vr = *(const f16x8*)(vb + (size_t)vtr * NN + 0 + vts * 8);
    *(f16x8*)(&klds[0][0] + ktr * KROW + kts * 8) = kr;
    *(f16x8*)(&vlds[0][0] + vtr * VROW + vts * 8) = vr;
    __syncthreads();
    kr = *(const f16x8*)(kb + (size_t)(64 + ktr) * 32 + kts * 8);
    vr = *(const f16x8*)(vb + (size_t)vtr * NN + 64 + vts * 8);

    for (int tile = 0; tile < NT - 2; tile++) {
        int buf = tile & 1;
        const f16* kl = &klds[buf][0];
        const f16* vl = &vlds[buf][0];
        KV32 f0 = lds_frags(kl, vl, 0, col, quad);
        KV32 f1 = lds_frags(kl, vl, 32, col, quad);
        compute32(f0, qB0, qB1, o00, o01, o10, o11, l0, l1);
        compute32(f1, qB0, qB1, o00, o01, o10, o11, l0, l1);
        *(f16x8*)(&klds[buf ^ 1][0] + ktr * KROW + kts * 8) = kr;
        *(f16x8*)(&vlds[buf ^ 1][0] + vtr * VROW + vts * 8) = vr;
        __syncthreads();
        int j0 = (tile + 2) * 64;
        kr = *(const f16x8*)(kb + (size_t)(j0 + ktr) * 32 + kts * 8);
        vr = *(const f16x8*)(vb + (size_t)vtr * NN + j0 + vts * 8);
    }
    {   // tile NT-2 (buf 0); kr/vr hold tile NT-1
        KV32 f0 = lds_frags(&klds[0][0], &vlds[0][0], 0, col, quad);
        KV32 f1 = lds_frags(&klds[0][0], &vlds[0][0], 32, col, quad);
        compute32(f0, qB0, qB1, o00, o01, o10, o11, l0, l1);
        compute32(f1, qB0, qB1, o00, o01, o10, o11, l0, l1);
        *(f16x8*)(&klds[1][0] + ktr * KROW + kts * 8) = kr;
        *(f16x8*)(&vlds[1][0] + vtr * VROW + vts * 8) = vr;
        __syncthreads();
    }
    {   // tile NT-1 (buf 1)
        KV32 f0 = lds_frags(&klds[1][0], &vlds[1][0], 0, col, quad);
        KV32 f1 = lds_frags(&klds[1][0], &vlds[1][0], 32, col, quad);
        compute32(f0, qB0, qB1, o00, o01, o10, o11, l0, l1);
        compute32(f1, qB0, qB1, o00, o01, o10, o11, l0, l1);
    }

    l0 += __shfl_xor(l0, 16); l0 += __shfl_xor(l0, 32);
    l1 += __shfl_xor(l1, 16); l1 += __shfl_xor(l1, 32);

    if constexpr (SPLIT == 1) {
        int b = bh >> 2, h = bh & 3;
        f16* ab = att16 + (size_t)b * NN * HID + h * 32;
#pragma unroll
        for (int r = 0; r < 4; r++) {
            float inv0 = __builtin_amdgcn_rcpf(__shfl(l0, quad * 4 + r));
            float inv1 = __builtin_amdgcn_rcpf(__shfl(l1, quad * 4 + r));
            size_t row0 = (size_t)(iw + quad * 4 + r) * HID;
            size_t row1 = (size_t)(iw + 16 + quad * 4 + r) * HID;
            ab[row0 + col]      = (f16)(o00[r] * inv0);
            ab[row0 + 16 + col] = (f16)(o01[r] * inv0);
            ab[row1 + col]      = (f16)(o10[r] * inv1);
            ab[row1 + 16 + col] = (f16)(o11[r] * inv1);
        }
    } else {
        // f32 partials: op[(s*16+bh)][q][dh], lp[(s*16+bh)][q]
        float* ob = op + (size_t)(s * 16 + bh) * NN * 32;
#pragma unroll
        for (int r = 0; r < 4; r++) {
            size_t r0 = (size_t)(iw + quad * 4 + r) * 32;
            size_t r1 = (size_t)(iw + 16 + quad * 4 + r) * 32;
            ob[r0 + col]      = o00[r];
            ob[r0 + 16 + col] = o01[r];
            ob[r1 + col]      = o10[r];
            ob[r1 + 16 + col] = o11[r];
        }
        if (quad == 0) {
            lp[(size_t)(s * 16 + bh) * NN + iw + col]      = l0;
            lp[(size_t)(s * 16 + bh) * NN + iw + 16 + col] = l1;
        }
    }
}

// ---------------- kernel 2b: combine split partials -> att16 ----------------
__global__ __launch_bounds__(256) void attn_combine(const float* __restrict__ op,
                                                    const float* __restrict__ lp,
                                                    f16* __restrict__ att16,
                                                    int nsplit) {
    int gid = blockIdx.x * 256 + threadIdx.x;   // 16*4096 rows * 8 segs
    int rowid = gid >> 3;
    int seg = gid & 7;
    int bh = rowid >> 12;
    int q = rowid & 4095;

    float l = 0.f;
    f32x4 acc = {0.f, 0.f, 0.f, 0.f};
    for (int s = 0; s < nsplit; s++) {
        l += lp[(size_t)(s * 16 + bh) * NN + q];
        f32x4 a = *(const f32x4*)(op + ((size_t)(s * 16 + bh) * NN + q) * 32 + seg * 4);
        acc += a;
    }
    float inv = __builtin_amdgcn_rcpf(l);
    int b = bh >> 2, h = bh & 3;
    f16x4 st;
    st[0] = (f16)(acc[0] * inv);
    st[1] = (f16)(acc[1] * inv);
    st[2] = (f16)(acc[2] * inv);
    st[3] = (f16)(acc[3] * inv);
    *(f16x4*)(att16 + ((size_t)b * NN + q) * HID + h * 32 + seg * 4) = st;
}

// ---------------- kernel 3: output projection (MFMA) + bias ----------------
__global__ __launch_bounds__(256) void out_mfma(const f16* __restrict__ att16,
                                                const float* __restrict__ wo,
                                                const float* __restrict__ bo,
                                                float* __restrict__ out) {
    int wave = threadIdx.x >> 6, lane = threadIdx.x & 63;
    int quad = lane >> 4, col = lane & 15;
    int b = blockIdx.z;
    int i0 = (blockIdx.x * 4 + wave) * 32;
    int o0 = blockIdx.y * 64;
    const f16* ab = att16 + (size_t)b * NN * HID;

    const f32x4 z = {0.f, 0.f, 0.f, 0.f};
    f32x4 c[2][4];
#pragma unroll
    for (int it = 0; it < 2; it++)
#pragma unroll
        for (int ot = 0; ot < 4; ot++) c[it][ot] = z;

#pragma unroll
    for (int k0 = 0; k0 < HID; k0 += 32) {
        f16x8 a0 = *(const f16x8*)(ab + (size_t)(i0 + col) * HID + k0 + quad * 8);
        f16x8 a1 = *(const f16x8*)(ab + (size_t)(i0 + 16 + col) * HID + k0 + quad * 8);
#pragma unroll
        for (int ot = 0; ot < 4; ot++) {
            f16x8 bf = cvt8(wo + (size_t)(o0 + ot * 16 + col) * HID + k0 + quad * 8);
            c[0][ot] = __builtin_amdgcn_mfma_f32_16x16x32_f16(a0, bf, c[0][ot], 0, 0, 0);
            c[1][ot] = __builtin_amdgcn_mfma_f32_16x16x32_f16(a1, bf, c[1][ot], 0, 0, 0);
        }
    }

#pragma unroll
    for (int it = 0; it < 2; it++)
#pragma unroll
        for (int ot = 0; ot < 4; ot++) {
            int o = o0 + ot * 16 + col;
            float bias = bo[o];
            int i = i0 + it * 16 + quad * 4;
            float4 st = {c[it][ot][0] + bias, c[it][ot][1] + bias,
                         c[it][ot][2] + bias, c[it][ot][3] + bias};
            *(float4*)(out + ((size_t)b * CC + o) * NN + i) = st;
        }
}

extern "C" void kernel_launch(void* const* d_in, const int* in_sizes, int n_in,
                              void* d_out, int out_size, void* d_ws, size_t ws_size,
                              hipStream_t stream) {
    const float* x     = (const float*)d_in[0];
    const float* w_qkv = (const float*)d_in[1];
    const float* w_out = (const float*)d_in[2];
    const float* b_out = (const float*)d_in[3];
    float* out = (float*)d_out;

    char* ws = (char*)d_ws;
    f16* qh    = (f16*)(ws);                        // 4 MB
    f16* kh    = (f16*)(ws + (4u << 20));           // 4 MB
    f16* vh    = (f16*)(ws + (8u << 20));           // 4 MB
    f16* att16 = (f16*)(ws + (12u << 20));          // 4 MB

    qkv_fused<<<dim3(NN / 128, 384 / 64, BB), 256, 0, stream>>>(x, w_qkv, qh, kh, vh);

    if (ws_size >= (50ull << 20)) {
        // SPLIT=4: op 32 MB @16MB, lp 1 MB @48MB -> 8 blocks/CU resident
        float* op = (float*)(ws + (16ull << 20));
        float* lp = (float*)(ws + (48ull << 20));
        attn_mfma<4><<<dim3(2048), 256, 0, stream>>>(qh, kh, vh, op, lp, att16);
        attn_combine<<<dim3(2048), 256, 0, stream>>>(op, lp, att16, 4);
    } else if (ws_size >= (33ull << 20)) {
        // SPLIT=2: op 16 MB @16MB, lp 0.5 MB @32MB -> 4 blocks/CU resident
        float* op = (float*)(ws + (16ull << 20));
        float* lp = (float*)(ws + (32ull << 20));
        attn_mfma<2><<<dim3(1024), 256, 0, stream>>>(qh, kh, vh, op, lp, att16);
        attn_combine<<<dim3(2048), 256, 0, stream>>>(op, lp, att16, 2);
    } else {
        attn_mfma<1><<<dim3(512), 256, 0, stream>>>(qh, kh, vh, nullptr, nullptr, att16);
    }

    out_mfma<<<dim3(NN / 128, CC / 64, BB), 256, 0, stream>>>(att16, w_out, b_out, out);
}

// Round 2
// 158.626 us; speedup vs baseline: 1.0545x; 1.0423x over previous
//
#include <hip/hip_runtime.h>
#include <math.h>

#define BB 4
#define CC 256
#define NHEAD 4
#define DH 32
#define NN 4096
#define HID 128

typedef _Float16 f16;
typedef _Float16 f16x8 __attribute__((ext_vector_type(8)));
typedef _Float16 f16x4 __attribute__((ext_vector_type(4)));
typedef _Float16 f16x2 __attribute__((ext_vector_type(2)));
typedef float f32x4 __attribute__((ext_vector_type(4)));
typedef unsigned int u32x4 __attribute__((ext_vector_type(4)));

#define QPRESCALE 14.42695041f
#define NSHIFT 14.42695041f

#if __has_builtin(__builtin_amdgcn_exp2f)
#define EXP2F(x) __builtin_amdgcn_exp2f(x)
#else
#define EXP2F(x) __expf((x)*0.6931471805599453f)
#endif

__device__ __forceinline__ f16x8 cvt8(const float* p) {
    float4 a = *(const float4*)p;
    float4 b = *(const float4*)(p + 4);
    f16x8 r;
    r[0] = (f16)a.x; r[1] = (f16)a.y; r[2] = (f16)a.z; r[3] = (f16)a.w;
    r[4] = (f16)b.x; r[5] = (f16)b.y; r[6] = (f16)b.z; r[7] = (f16)b.w;
    return r;
}

// ---------------- kernel 1: fused qkv GEMM + l2norm + layout ----------------
__global__ __launch_bounds__(256) void qkv_fused(const float* __restrict__ x,
                                                 const float* __restrict__ wq,
                                                 f16* __restrict__ qh,
                                                 f16* __restrict__ kh,
                                                 f16* __restrict__ vh) {
    int wave = threadIdx.x >> 6, lane = threadIdx.x & 63;
    int quad = lane >> 4, col = lane & 15;
    int b = blockIdx.z;
    int o0 = blockIdx.y * 64;
    int i0 = blockIdx.x * 128 + wave * 32;
    const float* xb = x + (size_t)b * CC * NN;

    f32x4 c[4][2];
#pragma unroll
    for (int mt = 0; mt < 4; mt++)
#pragma unroll
        for (int nt = 0; nt < 2; nt++) c[mt][nt] = f32x4{0.f, 0.f, 0.f, 0.f};

#pragma unroll
    for (int k0 = 0; k0 < CC; k0 += 32) {
        f16x8 a[4];
#pragma unroll
        for (int mt = 0; mt < 4; mt++)
            a[mt] = cvt8(wq + (size_t)(o0 + mt * 16 + col) * CC + k0 + quad * 8);
#pragma unroll
        for (int nt = 0; nt < 2; nt++) {
            const float* xc = xb + (size_t)(k0 + quad * 8) * NN + i0 + nt * 16 + col;
            f16x8 bf;
#pragma unroll
            for (int j = 0; j < 8; j++) bf[j] = (f16)xc[(size_t)j * NN];
#pragma unroll
            for (int mt = 0; mt < 4; mt++)
                c[mt][nt] = __builtin_amdgcn_mfma_f32_16x16x32_f16(a[mt], bf, c[mt][nt], 0, 0, 0);
        }
    }

    if (o0 < 256) {
        int isQ = (o0 < 128);
        int obase = isQ ? o0 : (o0 - 128);
        f16* dst = isQ ? qh : kh;
        float pre = isQ ? QPRESCALE : 1.0f;
#pragma unroll
        for (int nt = 0; nt < 2; nt++) {
#pragma unroll
            for (int hh = 0; hh < 2; hh++) {
                float ss = 0.f;
#pragma unroll
                for (int m2 = 0; m2 < 2; m2++)
#pragma unroll
                    for (int r = 0; r < 4; r++) {
                        float v = c[hh * 2 + m2][nt][r];
                        ss = fmaf(v, v, ss);
                    }
                ss += __shfl_xor(ss, 16);
                ss += __shfl_xor(ss, 32);
                float inv = pre / fmaxf(sqrtf(ss), 1e-12f);
                int h = (obase + hh * 32) >> 5;
                size_t row = ((size_t)(b * 4 + h) * NN + i0 + nt * 16 + col) * 32;
#pragma unroll
                for (int m2 = 0; m2 < 2; m2++) {
                    f16x4 st;
#pragma unroll
                    for (int r = 0; r < 4; r++) st[r] = (f16)(c[hh * 2 + m2][nt][r] * inv);
                    *(f16x4*)(dst + row + m2 * 16 + quad * 4) = st;
                }
            }
        }
    } else {
        int o2 = o0 - 256;
#pragma unroll
        for (int nt = 0; nt < 2; nt++) {
            int i = i0 + nt * 16 + col;
#pragma unroll
            for (int mt = 0; mt < 4; mt++) {
                int h = (o2 + mt * 16) >> 5;
                int d = (mt & 1) * 16 + quad * 4;
#pragma unroll
                for (int r = 0; r < 4; r++)
                    vh[((size_t)(b * 4 + h) * 32 + d + r) * NN + i] = (f16)c[mt][nt][r];
            }
        }
    }
}

// ---------------- kernel 2: LDS-staged MFMA flash attention, key-split ------
// R1 analysis: VALU 52% / Mfma 35% / 7.3M LDS conflicts -> throughput-bound,
// not latency. This version: (a) keys permuted at K-staging so QK output
// fragments concat directly into the 16x16x32 PV A-operand (PV MFMA count
// halves, K=16 shape eliminated); (b) V read as conflict-free b128 B-frags
// in natural [dh][key] order; (c) l accumulated on the MFMA pipe via a
// ones-B fragment (kills 24 VALU adds/tile + all epilogue shuffles);
// (d) explicit cvt_pkrtz packing for p.
#define KROW 40   // 32 d + 8 pad (f16) -> 80 B rows, b128 conflict-free
#define VROW 72   // 64 keys + 8 pad   -> 144 B rows, b128 conflict-free

struct G32 {
    f16x8 kA, kB;   // 32 permuted keys x 32 dh (two 16-row A-frags)
    f16x8 v0, v1;   // V[dh=col][32 keys], dh 0-15 / 16-31 B-frags
};

__device__ __forceinline__ G32 lds_frags32(const f16* kl, const f16* vl,
                                           int jb, int col, int quad) {
    G32 f;
    f.kA = *(const f16x8*)(kl + (jb + col) * KROW + quad * 8);
    f.kB = *(const f16x8*)(kl + (jb + 16 + col) * KROW + quad * 8);
    f.v0 = *(const f16x8*)(vl + col * VROW + jb + quad * 8);
    f.v1 = *(const f16x8*)(vl + (16 + col) * VROW + jb + quad * 8);
    return f;
}

__device__ __forceinline__ f16x8 expblk2(f32x4 sa, f32x4 sb) {
    u32x4 w;
    w[0] = __builtin_bit_cast(unsigned int,
            __builtin_amdgcn_cvt_pkrtz(EXP2F(sa[0]), EXP2F(sa[1])));
    w[1] = __builtin_bit_cast(unsigned int,
            __builtin_amdgcn_cvt_pkrtz(EXP2F(sa[2]), EXP2F(sa[3])));
    w[2] = __builtin_bit_cast(unsigned int,
            __builtin_amdgcn_cvt_pkrtz(EXP2F(sb[0]), EXP2F(sb[1])));
    w[3] = __builtin_bit_cast(unsigned int,
            __builtin_amdgcn_cvt_pkrtz(EXP2F(sb[2]), EXP2F(sb[3])));
    return __builtin_bit_cast(f16x8, w);
}

__device__ __forceinline__ void compute32g(const G32& f, f16x8 qB0, f16x8 qB1,
                                           f32x4& o00, f32x4& o01,
                                           f32x4& o10, f32x4& o11,
                                           f32x4& lf0, f32x4& lf1) {
    const f32x4 zs = {-NSHIFT, -NSHIFT, -NSHIFT, -NSHIFT};
    f16 one = (f16)1.0f;
    f16x8 ones = {one, one, one, one, one, one, one, one};
    f32x4 sa0 = __builtin_amdgcn_mfma_f32_16x16x32_f16(f.kA, qB0, zs, 0, 0, 0);
    f32x4 sb0 = __builtin_amdgcn_mfma_f32_16x16x32_f16(f.kB, qB0, zs, 0, 0, 0);
    f32x4 sa1 = __builtin_amdgcn_mfma_f32_16x16x32_f16(f.kA, qB1, zs, 0, 0, 0);
    f32x4 sb1 = __builtin_amdgcn_mfma_f32_16x16x32_f16(f.kB, qB1, zs, 0, 0, 0);
    f16x8 p0 = expblk2(sa0, sb0);
    f16x8 p1 = expblk2(sa1, sb1);
    o00 = __builtin_amdgcn_mfma_f32_16x16x32_f16(p0, f.v0, o00, 0, 0, 0);
    o01 = __builtin_amdgcn_mfma_f32_16x16x32_f16(p0, f.v1, o01, 0, 0, 0);
    lf0 = __builtin_amdgcn_mfma_f32_16x16x32_f16(p0, ones, lf0, 0, 0, 0);
    o10 = __builtin_amdgcn_mfma_f32_16x16x32_f16(p1, f.v0, o10, 0, 0, 0);
    o11 = __builtin_amdgcn_mfma_f32_16x16x32_f16(p1, f.v1, o11, 0, 0, 0);
    lf1 = __builtin_amdgcn_mfma_f32_16x16x32_f16(p1, ones, lf1, 0, 0, 0);
}

template <int SPLIT>
__global__ __launch_bounds__(256, 4) void attn_mfma(const f16* __restrict__ qh,
                                                    const f16* __restrict__ kh,
                                                    const f16* __restrict__ vh,
                                                    float* __restrict__ op,
                                                    float* __restrict__ lp,
                                                    f16* __restrict__ att16) {
    __shared__ __align__(16) f16 klds[2][64 * KROW];
    __shared__ __align__(16) f16 vlds[2][32 * VROW];
    int t = threadIdx.x;
    int wave = t >> 6, lane = t & 63;
    int quad = lane >> 4, col = lane & 15;

    int bid = blockIdx.x;
    int xcd = bid & 7;
    int slot = bid >> 3;                      // 0 .. 64*SPLIT-1
    int bh = xcd * 2 + slot / (32 * SPLIT);   // 0..15
    int rem = slot % (32 * SPLIT);
    int s = rem >> 5;                         // 0..SPLIT-1
    int i0 = (rem & 31) * 128;
    int iw = i0 + wave * 32;

    const int NT = 64 / SPLIT;                // 64-key tiles per block
    int kbase = s * (NN / SPLIT);

    const f16* qb = qh + (size_t)bh * NN * 32;
    const f16* kb = kh + (size_t)bh * NN * 32 + (size_t)kbase * 32;
    const f16* vb = vh + (size_t)bh * 32 * NN + kbase;

    f16x8 qB0 = *(const f16x8*)(qb + (size_t)(iw + col) * 32 + quad * 8);
    f16x8 qB1 = *(const f16x8*)(qb + (size_t)(iw + 16 + col) * 32 + quad * 8);

    f32x4 o00 = {0.f, 0.f, 0.f, 0.f}, o01 = o00, o10 = o00, o11 = o00;
    f32x4 lf0 = o00, lf1 = o00;

    // staging: K rows gathered in PV-permuted order so that P frag concat is
    // the native 16x16x32 A layout. ksrc is a bijection on 0..63:
    // row rho holds global key j0 + ksrc(rho).
    int ktr = t >> 2, kts = t & 3;
    int ksrc = (ktr & 32) | ((ktr & 12) << 1) | ((ktr & 16) >> 2) | (ktr & 3);
    int vtr = t >> 3, vts = t & 7;

    f16x8 kr, vr;
    kr = *(const f16x8*)(kb + (size_t)(0 + ksrc) * 32 + kts * 8);
    vr = *(const f16x8*)(vb + (size_t)vtr * NN + 0 + vts * 8);
    *(f16x8*)(&klds[0][0] + ktr * KROW + kts * 8) = kr;
    *(f16x8*)(&vlds[0][0] + vtr * VROW + vts * 8) = vr;
    __syncthreads();
    kr = *(const f16x8*)(kb + (size_t)(64 + ksrc) * 32 + kts * 8);
    vr = *(const f16x8*)(vb + (size_t)vtr * NN + 64 + vts * 8);

    for (int tile = 0; tile < NT - 2; tile++) {
        int buf = tile & 1;
        const f16* kl = &klds[buf][0];
        const f16* vl = &vlds[buf][0];
        G32 g0 = lds_frags32(kl, vl, 0, col, quad);
        G32 g1 = lds_frags32(kl, vl, 32, col, quad);
        compute32g(g0, qB0, qB1, o00, o01, o10, o11, lf0, lf1);
        compute32g(g1, qB0, qB1, o00, o01, o10, o11, lf0, lf1);
        *(f16x8*)(&klds[buf ^ 1][0] + ktr * KROW + kts * 8) = kr;
        *(f16x8*)(&vlds[buf ^ 1][0] + vtr * VROW + vts * 8) = vr;
        __syncthreads();
        int j0 = (tile + 2) * 64;
        kr = *(const f16x8*)(kb + (size_t)(j0 + ksrc) * 32 + kts * 8);
        vr = *(const f16x8*)(vb + (size_t)vtr * NN + j0 + vts * 8);
    }
    {   // tile NT-2 (buf 0); kr/vr hold tile NT-1
        G32 g0 = lds_frags32(&klds[0][0], &vlds[0][0], 0, col, quad);
        G32 g1 = lds_frags32(&klds[0][0], &vlds[0][0], 32, col, quad);
        compute32g(g0, qB0, qB1, o00, o01, o10, o11, lf0, lf1);
        compute32g(g1, qB0, qB1, o00, o01, o10, o11, lf0, lf1);
        *(f16x8*)(&klds[1][0] + ktr * KROW + kts * 8) = kr;
        *(f16x8*)(&vlds[1][0] + vtr * VROW + vts * 8) = vr;
        __syncthreads();
    }
    {   // tile NT-1 (buf 1)
        G32 g0 = lds_frags32(&klds[1][0], &vlds[1][0], 0, col, quad);
        G32 g1 = lds_frags32(&klds[1][0], &vlds[1][0], 32, col, quad);
        compute32g(g0, qB0, qB1, o00, o01, o10, o11, lf0, lf1);
        compute32g(g1, qB0, qB1, o00, o01, o10, o11, lf0, lf1);
    }

    // lf0[r] = sum_k p for query row quad*4+r (replicated across col lanes)
    if constexpr (SPLIT == 1) {
        int b = bh >> 2, h = bh & 3;
        f16* ab = att16 + (size_t)b * NN * HID + h * 32;
#pragma unroll
        for (int r = 0; r < 4; r++) {
            float inv0 = __builtin_amdgcn_rcpf(lf0[r]);
            float inv1 = __builtin_amdgcn_rcpf(lf1[r]);
            size_t row0 = (size_t)(iw + quad * 4 + r) * HID;
            size_t row1 = (size_t)(iw + 16 + quad * 4 + r) * HID;
            ab[row0 + col]      = (f16)(o00[r] * inv0);
            ab[row0 + 16 + col] = (f16)(o01[r] * inv0);
            ab[row1 + col]      = (f16)(o10[r] * inv1);
            ab[row1 + 16 + col] = (f16)(o11[r] * inv1);
        }
    } else {
        // f32 partials: op[(s*16+bh)][q][dh], lp[(s*16+bh)][q]
        float* ob = op + (size_t)(s * 16 + bh) * NN * 32;
#pragma unroll
        for (int r = 0; r < 4; r++) {
            size_t r0 = (size_t)(iw + quad * 4 + r) * 32;
            size_t r1 = (size_t)(iw + 16 + quad * 4 + r) * 32;
            ob[r0 + col]      = o00[r];
            ob[r0 + 16 + col] = o01[r];
            ob[r1 + col]      = o10[r];
            ob[r1 + 16 + col] = o11[r];
        }
        if (col == 0) {
            float* lb = lp + (size_t)(s * 16 + bh) * NN;
#pragma unroll
            for (int r = 0; r < 4; r++) {
                lb[iw + quad * 4 + r]      = lf0[r];
                lb[iw + 16 + quad * 4 + r] = lf1[r];
            }
        }
    }
}

// ---------------- kernel 2b: combine split partials -> att16 ----------------
__global__ __launch_bounds__(256) void attn_combine(const float* __restrict__ op,
                                                    const float* __restrict__ lp,
                                                    f16* __restrict__ att16,
                                                    int nsplit) {
    int gid = blockIdx.x * 256 + threadIdx.x;   // 16*4096 rows * 8 segs
    int rowid = gid >> 3;
    int seg = gid & 7;
    int bh = rowid >> 12;
    int q = rowid & 4095;

    float l = 0.f;
    f32x4 acc = {0.f, 0.f, 0.f, 0.f};
    for (int s = 0; s < nsplit; s++) {
        l += lp[(size_t)(s * 16 + bh) * NN + q];
        f32x4 a = *(const f32x4*)(op + ((size_t)(s * 16 + bh) * NN + q) * 32 + seg * 4);
        acc += a;
    }
    float inv = __builtin_amdgcn_rcpf(l);
    int b = bh >> 2, h = bh & 3;
    f16x4 st;
    st[0] = (f16)(acc[0] * inv);
    st[1] = (f16)(acc[1] * inv);
    st[2] = (f16)(acc[2] * inv);
    st[3] = (f16)(acc[3] * inv);
    *(f16x4*)(att16 + ((size_t)b * NN + q) * HID + h * 32 + seg * 4) = st;
}

// ---------------- kernel 3: output projection (MFMA) + bias ----------------
__global__ __launch_bounds__(256) void out_mfma(const f16* __restrict__ att16,
                                                const float* __restrict__ wo,
                                                const float* __restrict__ bo,
                                                float* __restrict__ out) {
    int wave = threadIdx.x >> 6, lane = threadIdx.x & 63;
    int quad = lane >> 4, col = lane & 15;
    int b = blockIdx.z;
    int i0 = (blockIdx.x * 4 + wave) * 32;
    int o0 = blockIdx.y * 64;
    const f16* ab = att16 + (size_t)b * NN * HID;

    const f32x4 z = {0.f, 0.f, 0.f, 0.f};
    f32x4 c[2][4];
#pragma unroll
    for (int it = 0; it < 2; it++)
#pragma unroll
        for (int ot = 0; ot < 4; ot++) c[it][ot] = z;

#pragma unroll
    for (int k0 = 0; k0 < HID; k0 += 32) {
        f16x8 a0 = *(const f16x8*)(ab + (size_t)(i0 + col) * HID + k0 + quad * 8);
        f16x8 a1 = *(const f16x8*)(ab + (size_t)(i0 + 16 + col) * HID + k0 + quad * 8);
#pragma unroll
        for (int ot = 0; ot < 4; ot++) {
            f16x8 bf = cvt8(wo + (size_t)(o0 + ot * 16 + col) * HID + k0 + quad * 8);
            c[0][ot] = __builtin_amdgcn_mfma_f32_16x16x32_f16(a0, bf, c[0][ot], 0, 0, 0);
            c[1][ot] = __builtin_amdgcn_mfma_f32_16x16x32_f16(a1, bf, c[1][ot], 0, 0, 0);
        }
    }

#pragma unroll
    for (int it = 0; it < 2; it++)
#pragma unroll
        for (int ot = 0; ot < 4; ot++) {
            int o = o0 + ot * 16 + col;
            float bias = bo[o];
            int i = i0 + it * 16 + quad * 4;
            float4 st = {c[it][ot][0] + bias, c[it][ot][1] + bias,
                         c[it][ot][2] + bias, c[it][ot][3] + bias};
            *(float4*)(out + ((size_t)b * CC + o) * NN + i) = st;
        }
}

extern "C" void kernel_launch(void* const* d_in, const int* in_sizes, int n_in,
                              void* d_out, int out_size, void* d_ws, size_t ws_size,
                              hipStream_t stream) {
    const float* x     = (const float*)d_in[0];
    const float* w_qkv = (const float*)d_in[1];
    const float* w_out = (const float*)d_in[2];
    const float* b_out = (const float*)d_in[3];
    float* out = (float*)d_out;

    char* ws = (char*)d_ws;
    f16* qh    = (f16*)(ws);                        // 4 MB
    f16* kh    = (f16*)(ws + (4u << 20));           // 4 MB
    f16* vh    = (f16*)(ws + (8u << 20));           // 4 MB
    f16* att16 = (f16*)(ws + (12u << 20));          // 4 MB

    qkv_fused<<<dim3(NN / 128, 384 / 64, BB), 256, 0, stream>>>(x, w_qkv, qh, kh, vh);

    if (ws_size >= (50ull << 20)) {
        // SPLIT=4: op 32 MB @16MB, lp 1 MB @48MB
        float* op = (float*)(ws + (16ull << 20));
        float* lp = (float*)(ws + (48ull << 20));
        attn_mfma<4><<<dim3(2048), 256, 0, stream>>>(qh, kh, vh, op, lp, att16);
        attn_combine<<<dim3(2048), 256, 0, stream>>>(op, lp, att16, 4);
    } else if (ws_size >= (33ull << 20)) {
        // SPLIT=2: op 16 MB @16MB, lp 0.5 MB @32MB
        float* op = (float*)(ws + (16ull << 20));
        float* lp = (float*)(ws + (32ull << 20));
        attn_mfma<2><<<dim3(1024), 256, 0, stream>>>(qh, kh, vh, op, lp, att16);
        attn_combine<<<dim3(2048), 256, 0, stream>>>(op, lp, att16, 2);
    } else {
        attn_mfma<1><<<dim3(512), 256, 0, stream>>>(qh, kh, vh, nullptr, nullptr, att16);
    }

    out_mfma<<<dim3(NN / 128, CC / 64, BB), 256, 0, stream>>>(att16, w_out, b_out, out);
}

// Round 3
// 154.989 us; speedup vs baseline: 1.0793x; 1.0235x over previous
//
#include <hip/hip_runtime.h>
#include <math.h>

#define BB 4
#define CC 256
#define NHEAD 4
#define DH 32
#define NN 4096
#define HID 128

typedef _Float16 f16;
typedef _Float16 f16x8 __attribute__((ext_vector_type(8)));
typedef _Float16 f16x4 __attribute__((ext_vector_type(4)));
typedef float f32x4 __attribute__((ext_vector_type(4)));
typedef unsigned int u32x4 __attribute__((ext_vector_type(4)));

#define QPRESCALE 14.42695041f
#define NSHIFT 14.42695041f

#if __has_builtin(__builtin_amdgcn_exp2f)
#define EXP2F(x) __builtin_amdgcn_exp2f(x)
#else
#define EXP2F(x) __expf((x)*0.6931471805599453f)
#endif

__device__ __forceinline__ f16x8 cvt8(const float* p) {
    float4 a = *(const float4*)p;
    float4 b = *(const float4*)(p + 4);
    f16x8 r;
    r[0] = (f16)a.x; r[1] = (f16)a.y; r[2] = (f16)a.z; r[3] = (f16)a.w;
    r[4] = (f16)b.x; r[5] = (f16)b.y; r[6] = (f16)b.z; r[7] = (f16)b.w;
    return r;
}

// ---------------- kernel 1: fused qkv GEMM + l2norm + layout ----------------
__global__ __launch_bounds__(256) void qkv_fused(const float* __restrict__ x,
                                                 const float* __restrict__ wq,
                                                 f16* __restrict__ qh,
                                                 f16* __restrict__ kh,
                                                 f16* __restrict__ vh) {
    int wave = threadIdx.x >> 6, lane = threadIdx.x & 63;
    int quad = lane >> 4, col = lane & 15;
    int b = blockIdx.z;
    int o0 = blockIdx.y * 64;
    int i0 = blockIdx.x * 128 + wave * 32;
    const float* xb = x + (size_t)b * CC * NN;

    f32x4 c[4][2];
#pragma unroll
    for (int mt = 0; mt < 4; mt++)
#pragma unroll
        for (int nt = 0; nt < 2; nt++) c[mt][nt] = f32x4{0.f, 0.f, 0.f, 0.f};

#pragma unroll
    for (int k0 = 0; k0 < CC; k0 += 32) {
        f16x8 a[4];
#pragma unroll
        for (int mt = 0; mt < 4; mt++)
            a[mt] = cvt8(wq + (size_t)(o0 + mt * 16 + col) * CC + k0 + quad * 8);
#pragma unroll
        for (int nt = 0; nt < 2; nt++) {
            const float* xc = xb + (size_t)(k0 + quad * 8) * NN + i0 + nt * 16 + col;
            f16x8 bf;
#pragma unroll
            for (int j = 0; j < 8; j++) bf[j] = (f16)xc[(size_t)j * NN];
#pragma unroll
            for (int mt = 0; mt < 4; mt++)
                c[mt][nt] = __builtin_amdgcn_mfma_f32_16x16x32_f16(a[mt], bf, c[mt][nt], 0, 0, 0);
        }
    }

    if (o0 < 256) {
        int isQ = (o0 < 128);
        int obase = isQ ? o0 : (o0 - 128);
        f16* dst = isQ ? qh : kh;
        float pre = isQ ? QPRESCALE : 1.0f;
#pragma unroll
        for (int nt = 0; nt < 2; nt++) {
#pragma unroll
            for (int hh = 0; hh < 2; hh++) {
                float ss = 0.f;
#pragma unroll
                for (int m2 = 0; m2 < 2; m2++)
#pragma unroll
                    for (int r = 0; r < 4; r++) {
                        float v = c[hh * 2 + m2][nt][r];
                        ss = fmaf(v, v, ss);
                    }
                ss += __shfl_xor(ss, 16);
                ss += __shfl_xor(ss, 32);
                float inv = pre / fmaxf(sqrtf(ss), 1e-12f);
                int h = (obase + hh * 32) >> 5;
                size_t row = ((size_t)(b * 4 + h) * NN + i0 + nt * 16 + col) * 32;
#pragma unroll
                for (int m2 = 0; m2 < 2; m2++) {
                    f16x4 st;
#pragma unroll
                    for (int r = 0; r < 4; r++) st[r] = (f16)(c[hh * 2 + m2][nt][r] * inv);
                    *(f16x4*)(dst + row + m2 * 16 + quad * 4) = st;
                }
            }
        }
    } else {
        int o2 = o0 - 256;
#pragma unroll
        for (int nt = 0; nt < 2; nt++) {
            int i = i0 + nt * 16 + col;
#pragma unroll
            for (int mt = 0; mt < 4; mt++) {
                int h = (o2 + mt * 16) >> 5;
                int d = (mt & 1) * 16 + quad * 4;
#pragma unroll
                for (int r = 0; r < 4; r++)
                    vh[((size_t)(b * 4 + h) * 32 + d + r) * NN + i] = (f16)c[mt][nt][r];
            }
        }
    }
}

// ---------------- kernel 2: LDS-staged MFMA flash attention, key-split ------
// R2 analysis: no pipe >50%; per-CU busy floors: MFMA ~20.6us, exp(trans)
// ~13.7us, LDS ~14us. All 4 waves of a block read the SAME K/V fragments, so
// frag traffic is q-invariant: this version gives each wave 64 q (4 q-frags,
// 256 q/block) -> LDS reads and misc VALU per S-element halve, and each wave
// carries 4 independent QK->exp->PV chains (exp of frag f overlaps MFMA of
// f-1/f+1). MFMA & exp per S-element unchanged (true floor).
#define KROW 40   // 32 d + 8 pad (f16) -> 80 B rows, b128-clean
#define VROW 72   // 64 keys + 8 pad   -> 144 B rows, b128-clean

__device__ __forceinline__ f16x8 expblk2(f32x4 sa, f32x4 sb) {
    u32x4 w;
    w[0] = __builtin_bit_cast(unsigned int,
            __builtin_amdgcn_cvt_pkrtz(EXP2F(sa[0]), EXP2F(sa[1])));
    w[1] = __builtin_bit_cast(unsigned int,
            __builtin_amdgcn_cvt_pkrtz(EXP2F(sa[2]), EXP2F(sa[3])));
    w[2] = __builtin_bit_cast(unsigned int,
            __builtin_amdgcn_cvt_pkrtz(EXP2F(sb[0]), EXP2F(sb[1])));
    w[3] = __builtin_bit_cast(unsigned int,
            __builtin_amdgcn_cvt_pkrtz(EXP2F(sb[2]), EXP2F(sb[3])));
    return __builtin_bit_cast(f16x8, w);
}

// one 32-key group (jb = 0 or 32) x 64 q (4 q-frags)
__device__ __forceinline__ void compute_g(const f16* kl, const f16* vl, int jb,
                                          int col, int quad, const f16x8 (&qB)[4],
                                          f32x4 (&o)[4][2], f32x4 (&lf)[4]) {
    f16x8 kA = *(const f16x8*)(kl + (jb + col) * KROW + quad * 8);
    f16x8 kB = *(const f16x8*)(kl + (jb + 16 + col) * KROW + quad * 8);
    f16x8 v0 = *(const f16x8*)(vl + col * VROW + jb + quad * 8);
    f16x8 v1 = *(const f16x8*)(vl + (16 + col) * VROW + jb + quad * 8);
    const f32x4 zs = {-NSHIFT, -NSHIFT, -NSHIFT, -NSHIFT};
    f16 one = (f16)1.0f;
    f16x8 ones = {one, one, one, one, one, one, one, one};
#pragma unroll
    for (int f = 0; f < 4; f++) {
        f32x4 sa = __builtin_amdgcn_mfma_f32_16x16x32_f16(kA, qB[f], zs, 0, 0, 0);
        f32x4 sb = __builtin_amdgcn_mfma_f32_16x16x32_f16(kB, qB[f], zs, 0, 0, 0);
        f16x8 p = expblk2(sa, sb);
        o[f][0] = __builtin_amdgcn_mfma_f32_16x16x32_f16(p, v0, o[f][0], 0, 0, 0);
        o[f][1] = __builtin_amdgcn_mfma_f32_16x16x32_f16(p, v1, o[f][1], 0, 0, 0);
        lf[f]   = __builtin_amdgcn_mfma_f32_16x16x32_f16(p, ones, lf[f], 0, 0, 0);
    }
}

template <int SPLIT>
__global__ __launch_bounds__(256, 4) void attn_mfma(const f16* __restrict__ qh,
                                                    const f16* __restrict__ kh,
                                                    const f16* __restrict__ vh,
                                                    float* __restrict__ op,
                                                    float* __restrict__ lp,
                                                    f16* __restrict__ att16) {
    __shared__ __align__(16) f16 klds[2][64 * KROW];
    __shared__ __align__(16) f16 vlds[2][32 * VROW];
    int t = threadIdx.x;
    int wave = t >> 6, lane = t & 63;
    int quad = lane >> 4, col = lane & 15;

    // grid = 256*SPLIT blocks; xcd grouping keeps K/V L2-resident (2 bh/XCD).
    int bid = blockIdx.x;
    int xcd = bid & 7;
    int slot = bid >> 3;                      // 0 .. 32*SPLIT-1
    int bh = xcd * 2 + slot / (16 * SPLIT);   // 0..15
    int rem = slot % (16 * SPLIT);
    int s = rem >> 4;                         // 0..SPLIT-1
    int i0 = (rem & 15) * 256;
    int iw = i0 + wave * 64;

    const int NT = 64 / SPLIT;                // 64-key tiles per block
    int kbase = s * (NN / SPLIT);

    const f16* qb = qh + (size_t)bh * NN * 32;
    const f16* kb = kh + (size_t)bh * NN * 32 + (size_t)kbase * 32;
    const f16* vb = vh + (size_t)bh * 32 * NN + kbase;

    f16x8 qB[4];
#pragma unroll
    for (int f = 0; f < 4; f++)
        qB[f] = *(const f16x8*)(qb + (size_t)(iw + f * 16 + col) * 32 + quad * 8);

    f32x4 o[4][2], lf[4];
#pragma unroll
    for (int f = 0; f < 4; f++) {
        o[f][0] = f32x4{0.f, 0.f, 0.f, 0.f};
        o[f][1] = f32x4{0.f, 0.f, 0.f, 0.f};
        lf[f]   = f32x4{0.f, 0.f, 0.f, 0.f};
    }

    // staging: K rows gathered in PV-permuted order (ksrc bijection) so P
    // frag concat is the native 16x16x32 A layout; V natural [dh][key].
    int ktr = t >> 2, kts = t & 3;
    int ksrc = (ktr & 32) | ((ktr & 12) << 1) | ((ktr & 16) >> 2) | (ktr & 3);
    int vtr = t >> 3, vts = t & 7;

    f16x8 kr, vr;
    kr = *(const f16x8*)(kb + (size_t)(0 + ksrc) * 32 + kts * 8);
    vr = *(const f16x8*)(vb + (size_t)vtr * NN + 0 + vts * 8);
    *(f16x8*)(&klds[0][0] + ktr * KROW + kts * 8) = kr;
    *(f16x8*)(&vlds[0][0] + vtr * VROW + vts * 8) = vr;
    __syncthreads();
    kr = *(const f16x8*)(kb + (size_t)(64 + ksrc) * 32 + kts * 8);
    vr = *(const f16x8*)(vb + (size_t)vtr * NN + 64 + vts * 8);

    for (int tile = 0; tile < NT - 2; tile++) {
        int buf = tile & 1;
        const f16* kl = &klds[buf][0];
        const f16* vl = &vlds[buf][0];
        compute_g(kl, vl, 0, col, quad, qB, o, lf);
        compute_g(kl, vl, 32, col, quad, qB, o, lf);
        *(f16x8*)(&klds[buf ^ 1][0] + ktr * KROW + kts * 8) = kr;
        *(f16x8*)(&vlds[buf ^ 1][0] + vtr * VROW + vts * 8) = vr;
        __syncthreads();
        int j0 = (tile + 2) * 64;
        kr = *(const f16x8*)(kb + (size_t)(j0 + ksrc) * 32 + kts * 8);
        vr = *(const f16x8*)(vb + (size_t)vtr * NN + j0 + vts * 8);
    }
    {   // tile NT-2 (buf 0); kr/vr hold tile NT-1
        compute_g(&klds[0][0], &vlds[0][0], 0, col, quad, qB, o, lf);
        compute_g(&klds[0][0], &vlds[0][0], 32, col, quad, qB, o, lf);
        *(f16x8*)(&klds[1][0] + ktr * KROW + kts * 8) = kr;
        *(f16x8*)(&vlds[1][0] + vtr * VROW + vts * 8) = vr;
        __syncthreads();
    }
    {   // tile NT-1 (buf 1)
        compute_g(&klds[1][0], &vlds[1][0], 0, col, quad, qB, o, lf);
        compute_g(&klds[1][0], &vlds[1][0], 32, col, quad, qB, o, lf);
    }

    // lf[f][r] = sum_k p for query row iw + f*16 + quad*4 + r (replicated
    // across col lanes).
    if constexpr (SPLIT == 1) {
        int b = bh >> 2, h = bh & 3;
        f16* ab = att16 + (size_t)b * NN * HID + h * 32;
#pragma unroll
        for (int f = 0; f < 4; f++)
#pragma unroll
            for (int r = 0; r < 4; r++) {
                float inv = __builtin_amdgcn_rcpf(lf[f][r]);
                size_t row = (size_t)(iw + f * 16 + quad * 4 + r) * HID;
                ab[row + col]      = (f16)(o[f][0][r] * inv);
                ab[row + 16 + col] = (f16)(o[f][1][r] * inv);
            }
    } else {
        // f32 partials: op[(s*16+bh)][q][dh], lp[(s*16+bh)][q]
        float* ob = op + (size_t)(s * 16 + bh) * NN * 32;
#pragma unroll
        for (int f = 0; f < 4; f++)
#pragma unroll
            for (int r = 0; r < 4; r++) {
                size_t rr = (size_t)(iw + f * 16 + quad * 4 + r) * 32;
                ob[rr + col]      = o[f][0][r];
                ob[rr + 16 + col] = o[f][1][r];
            }
        if (col == 0) {
            float* lb = lp + (size_t)(s * 16 + bh) * NN;
#pragma unroll
            for (int f = 0; f < 4; f++)
#pragma unroll
                for (int r = 0; r < 4; r++)
                    lb[iw + f * 16 + quad * 4 + r] = lf[f][r];
        }
    }
}

// ---------------- kernel 2b: combine split partials -> att16 ----------------
__global__ __launch_bounds__(256) void attn_combine(const float* __restrict__ op,
                                                    const float* __restrict__ lp,
                                                    f16* __restrict__ att16,
                                                    int nsplit) {
    int gid = blockIdx.x * 256 + threadIdx.x;   // 16*4096 rows * 8 segs
    int rowid = gid >> 3;
    int seg = gid & 7;
    int bh = rowid >> 12;
    int q = rowid & 4095;

    float l = 0.f;
    f32x4 acc = {0.f, 0.f, 0.f, 0.f};
    for (int s = 0; s < nsplit; s++) {
        l += lp[(size_t)(s * 16 + bh) * NN + q];
        f32x4 a = *(const f32x4*)(op + ((size_t)(s * 16 + bh) * NN + q) * 32 + seg * 4);
        acc += a;
    }
    float inv = __builtin_amdgcn_rcpf(l);
    int b = bh >> 2, h = bh & 3;
    f16x4 st;
    st[0] = (f16)(acc[0] * inv);
    st[1] = (f16)(acc[1] * inv);
    st[2] = (f16)(acc[2] * inv);
    st[3] = (f16)(acc[3] * inv);
    *(f16x4*)(att16 + ((size_t)b * NN + q) * HID + h * 32 + seg * 4) = st;
}

// ---------------- kernel 3: output projection (MFMA) + bias ----------------
__global__ __launch_bounds__(256) void out_mfma(const f16* __restrict__ att16,
                                                const float* __restrict__ wo,
                                                const float* __restrict__ bo,
                                                float* __restrict__ out) {
    int wave = threadIdx.x >> 6, lane = threadIdx.x & 63;
    int quad = lane >> 4, col = lane & 15;
    int b = blockIdx.z;
    int i0 = (blockIdx.x * 4 + wave) * 32;
    int o0 = blockIdx.y * 64;
    const f16* ab = att16 + (size_t)b * NN * HID;

    const f32x4 z = {0.f, 0.f, 0.f, 0.f};
    f32x4 c[2][4];
#pragma unroll
    for (int it = 0; it < 2; it++)
#pragma unroll
        for (int ot = 0; ot < 4; ot++) c[it][ot] = z;

#pragma unroll
    for (int k0 = 0; k0 < HID; k0 += 32) {
        f16x8 a0 = *(const f16x8*)(ab + (size_t)(i0 + col) * HID + k0 + quad * 8);
        f16x8 a1 = *(const f16x8*)(ab + (size_t)(i0 + 16 + col) * HID + k0 + quad * 8);
#pragma unroll
        for (int ot = 0; ot < 4; ot++) {
            f16x8 bf = cvt8(wo + (size_t)(o0 + ot * 16 + col) * HID + k0 + quad * 8);
            c[0][ot] = __builtin_amdgcn_mfma_f32_16x16x32_f16(a0, bf, c[0][ot], 0, 0, 0);
            c[1][ot] = __builtin_amdgcn_mfma_f32_16x16x32_f16(a1, bf, c[1][ot], 0, 0, 0);
        }
    }

#pragma unroll
    for (int it = 0; it < 2; it++)
#pragma unroll
        for (int ot = 0; ot < 4; ot++) {
            int o = o0 + ot * 16 + col;
            float bias = bo[o];
            int i = i0 + it * 16 + quad * 4;
            float4 st = {c[it][ot][0] + bias, c[it][ot][1] + bias,
                         c[it][ot][2] + bias, c[it][ot][3] + bias};
            *(float4*)(out + ((size_t)b * CC + o) * NN + i) = st;
        }
}

extern "C" void kernel_launch(void* const* d_in, const int* in_sizes, int n_in,
                              void* d_out, int out_size, void* d_ws, size_t ws_size,
                              hipStream_t stream) {
    const float* x     = (const float*)d_in[0];
    const float* w_qkv = (const float*)d_in[1];
    const float* w_out = (const float*)d_in[2];
    const float* b_out = (const float*)d_in[3];
    float* out = (float*)d_out;

    char* ws = (char*)d_ws;
    f16* qh    = (f16*)(ws);                        // 4 MB
    f16* kh    = (f16*)(ws + (4u << 20));           // 4 MB
    f16* vh    = (f16*)(ws + (8u << 20));           // 4 MB
    f16* att16 = (f16*)(ws + (12u << 20));          // 4 MB

    qkv_fused<<<dim3(NN / 128, 384 / 64, BB), 256, 0, stream>>>(x, w_qkv, qh, kh, vh);

    if (ws_size >= (50ull << 20)) {
        // SPLIT=4: op 32 MB @16MB, lp 1 MB @48MB; grid 1024 = 4 blocks/CU
        float* op = (float*)(ws + (16ull << 20));
        float* lp = (float*)(ws + (48ull << 20));
        attn_mfma<4><<<dim3(1024), 256, 0, stream>>>(qh, kh, vh, op, lp, att16);
        attn_combine<<<dim3(2048), 256, 0, stream>>>(op, lp, att16, 4);
    } else if (ws_size >= (33ull << 20)) {
        // SPLIT=2: op 16 MB @16MB, lp 0.5 MB @32MB
        float* op = (float*)(ws + (16ull << 20));
        float* lp = (float*)(ws + (32ull << 20));
        attn_mfma<2><<<dim3(512), 256, 0, stream>>>(qh, kh, vh, op, lp, att16);
        attn_combine<<<dim3(2048), 256, 0, stream>>>(op, lp, att16, 2);
    } else {
        attn_mfma<1><<<dim3(256), 256, 0, stream>>>(qh, kh, vh, nullptr, nullptr, att16);
    }

    out_mfma<<<dim3(NN / 128, CC / 64, BB), 256, 0, stream>>>(att16, w_out, b_out, out);
}